// Round 1
// baseline (232.263 us; speedup 1.0000x reference)
//
#include <hip/hip_runtime.h>

#define N_NODES 50000
#define N_EDGES 300000
#define D_FEAT 256
// Only layers 3 (256->32) and 4 (32->40) are live in the reference.

__global__ __launch_bounds__(256) void count_kernel(const int* __restrict__ ei,
                                                    float* __restrict__ cnt) {
    int e = blockIdx.x * 256 + threadIdx.x;
    if (e < N_EDGES) atomicAdd(&cnt[ei[N_EDGES + e]], 1.0f);
}

// xl = x @ Wl3, xr = x @ Wr3  (fused: one pass over x, 64 output cols)
__global__ __launch_bounds__(256) void proj3_kernel(const float* __restrict__ x,
        const float* __restrict__ Wl, const float* __restrict__ Wr,
        float* __restrict__ xl, float* __restrict__ xr) {
    __shared__ float w[128][64];
    const int tid = threadIdx.x;
    const int node = blockIdx.x * 256 + tid;
    float acc[64];
#pragma unroll
    for (int c = 0; c < 64; ++c) acc[c] = 0.0f;

    for (int kb = 0; kb < 2; ++kb) {
        __syncthreads();
#pragma unroll
        for (int i = 0; i < 32; ++i) {
            int idx = tid + i * 256;
            int k = idx >> 6, c = idx & 63;
            int gk = kb * 128 + k;
            w[k][c] = (c < 32) ? Wl[gk * 32 + c] : Wr[gk * 32 + (c - 32)];
        }
        __syncthreads();
        if (node < N_NODES) {
            const float4* xrow = (const float4*)(x + (size_t)node * D_FEAT + kb * 128);
#pragma unroll 4
            for (int k4 = 0; k4 < 32; ++k4) {
                float4 xv = xrow[k4];
                float xs0 = xv.x, xs1 = xv.y, xs2 = xv.z, xs3 = xv.w;
                int k = k4 * 4;
#pragma unroll
                for (int c4 = 0; c4 < 16; ++c4) {
                    float4 w0 = *(const float4*)&w[k + 0][c4 * 4];
                    float4 w1 = *(const float4*)&w[k + 1][c4 * 4];
                    float4 w2 = *(const float4*)&w[k + 2][c4 * 4];
                    float4 w3 = *(const float4*)&w[k + 3][c4 * 4];
                    acc[c4 * 4 + 0] += xs0 * w0.x + xs1 * w1.x + xs2 * w2.x + xs3 * w3.x;
                    acc[c4 * 4 + 1] += xs0 * w0.y + xs1 * w1.y + xs2 * w2.y + xs3 * w3.y;
                    acc[c4 * 4 + 2] += xs0 * w0.z + xs1 * w1.z + xs2 * w2.z + xs3 * w3.z;
                    acc[c4 * 4 + 3] += xs0 * w0.w + xs1 * w1.w + xs2 * w2.w + xs3 * w3.w;
                }
            }
        }
    }
    if (node < N_NODES) {
        float4* xlp = (float4*)(xl + (size_t)node * 32);
        float4* xrp = (float4*)(xr + (size_t)node * 32);
#pragma unroll
        for (int q = 0; q < 8; ++q) {
            xlp[q] = make_float4(acc[q * 4 + 0], acc[q * 4 + 1], acc[q * 4 + 2], acc[q * 4 + 3]);
            xrp[q] = make_float4(acc[32 + q * 4 + 0], acc[32 + q * 4 + 1],
                                 acc[32 + q * 4 + 2], acc[32 + q * 4 + 3]);
        }
    }
}

__global__ __launch_bounds__(256) void scatter3_kernel(const int* __restrict__ ei,
        const float* __restrict__ xl, float* __restrict__ agg3) {
    int gid = blockIdx.x * 256 + threadIdx.x;
    if (gid >= N_EDGES * 32) return;
    int e = gid >> 5, c = gid & 31;
    int s = ei[e], d = ei[N_EDGES + e];
    atomicAdd(&agg3[(size_t)d * 32 + c], xl[(size_t)s * 32 + c]);
}

// h = relu(agg3/cnt + xr + b3); hl = h @ Wl4; hr = h @ Wr4
__global__ __launch_bounds__(256) void layer4_kernel(const float* __restrict__ agg3,
        const float* __restrict__ xr3, const float* __restrict__ cnt,
        const float* __restrict__ b3, const float* __restrict__ Wl4,
        const float* __restrict__ Wr4, float* __restrict__ hl, float* __restrict__ hr) {
    __shared__ float w[32][80];
    const int tid = threadIdx.x;
    for (int i = tid; i < 32 * 80; i += 256) {
        int k = i / 80, c = i - k * 80;
        w[k][c] = (c < 40) ? Wl4[k * 40 + c] : Wr4[k * 40 + (c - 40)];
    }
    __syncthreads();
    const int node = blockIdx.x * 256 + tid;
    if (node >= N_NODES) return;
    const float inv = 1.0f / fmaxf(cnt[node], 1.0f);
    float h[32];
    const float4* ap = (const float4*)(agg3 + (size_t)node * 32);
    const float4* xp = (const float4*)(xr3 + (size_t)node * 32);
#pragma unroll
    for (int q = 0; q < 8; ++q) {
        float4 a = ap[q];
        float4 b = xp[q];
        h[q * 4 + 0] = fmaxf(a.x * inv + b.x + b3[q * 4 + 0], 0.0f);
        h[q * 4 + 1] = fmaxf(a.y * inv + b.y + b3[q * 4 + 1], 0.0f);
        h[q * 4 + 2] = fmaxf(a.z * inv + b.z + b3[q * 4 + 2], 0.0f);
        h[q * 4 + 3] = fmaxf(a.w * inv + b.w + b3[q * 4 + 3], 0.0f);
    }
    float acc[80];
#pragma unroll
    for (int c = 0; c < 80; ++c) acc[c] = 0.0f;
#pragma unroll 8
    for (int k = 0; k < 32; ++k) {
        float hv = h[k];
#pragma unroll
        for (int c4 = 0; c4 < 20; ++c4) {
            float4 wv = *(const float4*)&w[k][c4 * 4];
            acc[c4 * 4 + 0] += hv * wv.x;
            acc[c4 * 4 + 1] += hv * wv.y;
            acc[c4 * 4 + 2] += hv * wv.z;
            acc[c4 * 4 + 3] += hv * wv.w;
        }
    }
    float4* hlp = (float4*)(hl + (size_t)node * 40);
    float4* hrp = (float4*)(hr + (size_t)node * 40);
#pragma unroll
    for (int q = 0; q < 10; ++q) {
        hlp[q] = make_float4(acc[q * 4 + 0], acc[q * 4 + 1], acc[q * 4 + 2], acc[q * 4 + 3]);
        hrp[q] = make_float4(acc[40 + q * 4 + 0], acc[40 + q * 4 + 1],
                             acc[40 + q * 4 + 2], acc[40 + q * 4 + 3]);
    }
}

__global__ __launch_bounds__(256) void scatter4_kernel(const int* __restrict__ ei,
        const float* __restrict__ hl, float* __restrict__ agg4) {
    int gid = blockIdx.x * 256 + threadIdx.x;
    if (gid >= N_EDGES * 40) return;
    int e = gid / 40, c = gid - e * 40;
    int s = ei[e], d = ei[N_EDGES + e];
    atomicAdd(&agg4[(size_t)d * 40 + c], hl[(size_t)s * 40 + c]);
}

__global__ __launch_bounds__(256) void out_kernel(const float* __restrict__ agg4,
        const float* __restrict__ hr, const float* __restrict__ cnt,
        const float* __restrict__ b4, float* __restrict__ out) {
    const int node = blockIdx.x * 256 + threadIdx.x;
    if (node >= N_NODES) return;
    const float inv = 1.0f / fmaxf(cnt[node], 1.0f);
    float v[40];
    const float4* ap = (const float4*)(agg4 + (size_t)node * 40);
    const float4* hp = (const float4*)(hr + (size_t)node * 40);
#pragma unroll
    for (int q = 0; q < 10; ++q) {
        float4 a = ap[q];
        float4 b = hp[q];
        v[q * 4 + 0] = a.x * inv + b.x + b4[q * 4 + 0];
        v[q * 4 + 1] = a.y * inv + b.y + b4[q * 4 + 1];
        v[q * 4 + 2] = a.z * inv + b.z + b4[q * 4 + 2];
        v[q * 4 + 3] = a.w * inv + b.w + b4[q * 4 + 3];
    }
    float m = v[0];
#pragma unroll
    for (int c = 1; c < 40; ++c) m = fmaxf(m, v[c]);
    float s = 0.0f;
#pragma unroll
    for (int c = 0; c < 40; ++c) s += expf(v[c] - m);
    const float ls = logf(s);
    float4* op = (float4*)(out + (size_t)node * 40);
#pragma unroll
    for (int q = 0; q < 10; ++q)
        op[q] = make_float4(v[q * 4 + 0] - m - ls, v[q * 4 + 1] - m - ls,
                            v[q * 4 + 2] - m - ls, v[q * 4 + 3] - m - ls);
}

extern "C" void kernel_launch(void* const* d_in, const int* in_sizes, int n_in,
                              void* d_out, int out_size, void* d_ws, size_t ws_size,
                              hipStream_t stream) {
    const float* x   = (const float*)d_in[0];
    const int*   ei  = (const int*)d_in[1];
    const float* Wl3 = (const float*)d_in[8];
    const float* Wr3 = (const float*)d_in[9];
    const float* b3  = (const float*)d_in[10];
    const float* Wl4 = (const float*)d_in[11];
    const float* Wr4 = (const float*)d_in[12];
    const float* b4  = (const float*)d_in[13];
    float* outf = (float*)d_out;

    float* ws   = (float*)d_ws;
    float* cnt  = ws;                          // 50000
    float* agg3 = cnt + N_NODES;               // 50000*32
    float* agg4 = agg3 + (size_t)N_NODES * 32; // 50000*40
    float* xl   = agg4 + (size_t)N_NODES * 40; // 50000*32
    float* xr   = xl + (size_t)N_NODES * 32;   // 50000*32
    float* hl   = xr + (size_t)N_NODES * 32;   // 50000*40
    float* hr   = hl + (size_t)N_NODES * 40;   // 50000*40

    // zero cnt + agg3 + agg4 (contiguous at the front of ws)
    size_t zero_bytes = (size_t)(N_NODES + N_NODES * 32 + N_NODES * 40) * sizeof(float);
    hipMemsetAsync(d_ws, 0, zero_bytes, stream);

    count_kernel<<<(N_EDGES + 255) / 256, 256, 0, stream>>>(ei, cnt);
    proj3_kernel<<<(N_NODES + 255) / 256, 256, 0, stream>>>(x, Wl3, Wr3, xl, xr);
    scatter3_kernel<<<(N_EDGES * 32 + 255) / 256, 256, 0, stream>>>(ei, xl, agg3);
    layer4_kernel<<<(N_NODES + 255) / 256, 256, 0, stream>>>(agg3, xr, cnt, b3, Wl4, Wr4, hl, hr);
    scatter4_kernel<<<(N_EDGES * 40 + 255) / 256, 256, 0, stream>>>(ei, hl, agg4);
    out_kernel<<<(N_NODES + 255) / 256, 256, 0, stream>>>(agg4, hr, cnt, b4, outf);
}

// Round 2
// 137.694 us; speedup vs baseline: 1.6868x; 1.6868x over previous
//
#include <hip/hip_runtime.h>

#define N_NODES 50000
#define N_EDGES 300000
#define D_FEAT 256
// Only layers 3 (256->32) and 4 (32->40) are live in the reference:
// h = relu(mean_agg(x)@Wl3 + x@Wr3 + b3)
// out = log_softmax(mean_agg(h)@Wl4 + h@Wr4 + b4)
// Projection commutes with mean-aggregation -> project first, scatter in
// low-dim space (32 cols) for both layers.

typedef __attribute__((ext_vector_type(8))) short bf16x8;
typedef __attribute__((ext_vector_type(4))) float f32x4;

__device__ __forceinline__ unsigned short f2bf(float f) {
    unsigned int u = __builtin_bit_cast(unsigned int, f);
    u += 0x7fffu + ((u >> 16) & 1u);   // round-to-nearest-even
    return (unsigned short)(u >> 16);
}

__global__ __launch_bounds__(256) void count_kernel(const int* __restrict__ ei,
                                                    float* __restrict__ cnt) {
    int e = blockIdx.x * 256 + threadIdx.x;
    if (e < N_EDGES) atomicAdd(&cnt[ei[N_EDGES + e]], 1.0f);
}

// Pack [Wl3 | Wr3] (256x64 f32) into bf16 B-fragment order:
// bp[((nt*8+ks)*64+lane)*8 + j] = W(k= ks*32+(lane>>4)*8+j, c= nt*16+(lane&15))
__global__ __launch_bounds__(256) void wpack3_kernel(const float* __restrict__ Wl,
        const float* __restrict__ Wr, unsigned short* __restrict__ bp) {
    int t = blockIdx.x * 256 + threadIdx.x;
    if (t >= 2048) return;
    int lane = t & 63;
    int ks = (t >> 6) & 7;
    int nt = t >> 9;
    int c = nt * 16 + (lane & 15);
    int kbase = ks * 32 + (lane >> 4) * 8;
    unsigned short o[8];
#pragma unroll
    for (int j = 0; j < 8; ++j) {
        int k = kbase + j;
        float v = (c < 32) ? Wl[k * 32 + c] : Wr[k * 32 + (c - 32)];
        o[j] = f2bf(v);
    }
    uint4 pk;
    pk.x = (unsigned)o[0] | ((unsigned)o[1] << 16);
    pk.y = (unsigned)o[2] | ((unsigned)o[3] << 16);
    pk.z = (unsigned)o[4] | ((unsigned)o[5] << 16);
    pk.w = (unsigned)o[6] | ((unsigned)o[7] << 16);
    ((uint4*)bp)[t] = pk;
}

// xl = x @ Wl3, xr = x @ Wr3 via bf16 MFMA. Block=256 (4 waves), each wave
// owns 16 rows; no LDS, B-frags from L2-resident packed weights.
__global__ __launch_bounds__(256) void proj3_mfma(const float* __restrict__ x,
        const unsigned short* __restrict__ bp,
        float* __restrict__ xl, float* __restrict__ xr) {
    const int lane = threadIdx.x & 63;
    const int wv = threadIdx.x >> 6;
    const int row0 = blockIdx.x * 64 + wv * 16;
    const int arow = row0 + (lane & 15);
    const int kq = lane >> 4;
    const bool valid = arow < N_NODES;

    bf16x8 a[8];
    const float* xp = x + (size_t)arow * D_FEAT + kq * 8;
#pragma unroll
    for (int ks = 0; ks < 8; ++ks) {
        float4 p0, p1;
        if (valid) {
            p0 = *(const float4*)(xp + ks * 32);
            p1 = *(const float4*)(xp + ks * 32 + 4);
        } else {
            p0 = make_float4(0.f, 0.f, 0.f, 0.f);
            p1 = p0;
        }
        bf16x8 av;
        av[0] = (short)f2bf(p0.x); av[1] = (short)f2bf(p0.y);
        av[2] = (short)f2bf(p0.z); av[3] = (short)f2bf(p0.w);
        av[4] = (short)f2bf(p1.x); av[5] = (short)f2bf(p1.y);
        av[6] = (short)f2bf(p1.z); av[7] = (short)f2bf(p1.w);
        a[ks] = av;
    }

    f32x4 acc[4];
#pragma unroll
    for (int nt = 0; nt < 4; ++nt) acc[nt] = (f32x4){0.f, 0.f, 0.f, 0.f};

    const uint4* bq = (const uint4*)bp;
#pragma unroll
    for (int nt = 0; nt < 4; ++nt) {
#pragma unroll
        for (int ks = 0; ks < 8; ++ks) {
            bf16x8 b = __builtin_bit_cast(bf16x8, bq[(nt * 8 + ks) * 64 + lane]);
            acc[nt] = __builtin_amdgcn_mfma_f32_16x16x32_bf16(a[ks], b, acc[nt], 0, 0, 0);
        }
    }

    // C/D: col = lane&15, row = (lane>>4)*4 + reg
    const int orow = row0 + (lane >> 4) * 4;
    const int ocol = lane & 15;
#pragma unroll
    for (int nt = 0; nt < 4; ++nt) {
        float* dst = (nt < 2) ? xl : xr;
        const int cc = (nt & 1) * 16 + ocol;
#pragma unroll
        for (int i = 0; i < 4; ++i) {
            int r = orow + i;
            if (r < N_NODES) dst[(size_t)r * 32 + cc] = acc[nt][i];
        }
    }
}

// agg[dst][c] += feat[src][c], 32 cols per edge
__global__ __launch_bounds__(256) void scatter32_kernel(const int* __restrict__ ei,
        const float* __restrict__ feat, float* __restrict__ agg) {
    int gid = blockIdx.x * 256 + threadIdx.x;
    if (gid >= N_EDGES * 32) return;
    int e = gid >> 5, c = gid & 31;
    int s = ei[e], d = ei[N_EDGES + e];
    atomicAdd(&agg[(size_t)d * 32 + c], feat[(size_t)s * 32 + c]);
}

// h = relu(agg3/cnt + xr + b3), one float4 per thread
__global__ __launch_bounds__(256) void h_kernel(const float* __restrict__ agg3,
        const float* __restrict__ xr3, const float* __restrict__ cnt,
        const float* __restrict__ b3, float* __restrict__ h) {
    int gid = blockIdx.x * 256 + threadIdx.x;
    if (gid >= N_NODES * 8) return;
    int node = gid >> 3, q = gid & 7;
    float inv = 1.0f / fmaxf(cnt[node], 1.0f);
    float4 a = ((const float4*)agg3)[gid];
    float4 b = ((const float4*)xr3)[gid];
    float4 bb = ((const float4*)b3)[q];
    float4 r;
    r.x = fmaxf(fmaf(a.x, inv, b.x) + bb.x, 0.0f);
    r.y = fmaxf(fmaf(a.y, inv, b.y) + bb.y, 0.0f);
    r.z = fmaxf(fmaf(a.z, inv, b.z) + bb.z, 0.0f);
    r.w = fmaxf(fmaf(a.w, inv, b.w) + bb.w, 0.0f);
    ((float4*)h)[gid] = r;
}

// out = log_softmax((agg4h/cnt)@Wl4 + h@Wr4 + b4)
__global__ __launch_bounds__(256) void out_kernel(const float* __restrict__ agg4h,
        const float* __restrict__ h, const float* __restrict__ cnt,
        const float* __restrict__ Wl4, const float* __restrict__ Wr4,
        const float* __restrict__ b4, float* __restrict__ out) {
    __shared__ float w[32][80];
    const int tid = threadIdx.x;
    for (int i = tid; i < 32 * 80; i += 256) {
        int k = i / 80, c = i - k * 80;
        w[k][c] = (c < 40) ? Wl4[k * 40 + c] : Wr4[k * 40 + (c - 40)];
    }
    __syncthreads();
    const int node = blockIdx.x * 256 + tid;
    if (node >= N_NODES) return;
    const float inv = 1.0f / fmaxf(cnt[node], 1.0f);
    float acc[40];
#pragma unroll
    for (int c = 0; c < 40; ++c) acc[c] = b4[c];
    const float4* ap = (const float4*)(agg4h + (size_t)node * 32);
    const float4* hp = (const float4*)(h + (size_t)node * 32);
#pragma unroll
    for (int q = 0; q < 8; ++q) {
        float4 av = ap[q];
        float4 hv = hp[q];
        float mk[4] = {av.x * inv, av.y * inv, av.z * inv, av.w * inv};
        float hk[4] = {hv.x, hv.y, hv.z, hv.w};
#pragma unroll
        for (int j = 0; j < 4; ++j) {
            const int k = q * 4 + j;
#pragma unroll
            for (int c4 = 0; c4 < 10; ++c4) {
                float4 wl = *(const float4*)&w[k][c4 * 4];
                float4 wr = *(const float4*)&w[k][40 + c4 * 4];
                acc[c4 * 4 + 0] += mk[j] * wl.x + hk[j] * wr.x;
                acc[c4 * 4 + 1] += mk[j] * wl.y + hk[j] * wr.y;
                acc[c4 * 4 + 2] += mk[j] * wl.z + hk[j] * wr.z;
                acc[c4 * 4 + 3] += mk[j] * wl.w + hk[j] * wr.w;
            }
        }
    }
    float m = acc[0];
#pragma unroll
    for (int c = 1; c < 40; ++c) m = fmaxf(m, acc[c]);
    float s = 0.0f;
#pragma unroll
    for (int c = 0; c < 40; ++c) s += expf(acc[c] - m);
    const float ls = logf(s) + m;
    float4* op = (float4*)(out + (size_t)node * 40);
#pragma unroll
    for (int q = 0; q < 10; ++q)
        op[q] = make_float4(acc[q * 4 + 0] - ls, acc[q * 4 + 1] - ls,
                            acc[q * 4 + 2] - ls, acc[q * 4 + 3] - ls);
}

extern "C" void kernel_launch(void* const* d_in, const int* in_sizes, int n_in,
                              void* d_out, int out_size, void* d_ws, size_t ws_size,
                              hipStream_t stream) {
    const float* x   = (const float*)d_in[0];
    const int*   ei  = (const int*)d_in[1];
    const float* Wl3 = (const float*)d_in[8];
    const float* Wr3 = (const float*)d_in[9];
    const float* b3  = (const float*)d_in[10];
    const float* Wl4 = (const float*)d_in[11];
    const float* Wr4 = (const float*)d_in[12];
    const float* b4  = (const float*)d_in[13];
    float* outf = (float*)d_out;

    float* ws    = (float*)d_ws;
    float* cnt   = ws;                            // 50000
    float* agg3  = cnt + N_NODES;                 // 50000*32
    float* agg4h = agg3 + (size_t)N_NODES * 32;   // 50000*32
    float* xl    = agg4h + (size_t)N_NODES * 32;  // 50000*32
    float* xr    = xl + (size_t)N_NODES * 32;     // 50000*32
    float* h     = xr + (size_t)N_NODES * 32;     // 50000*32
    unsigned short* bpack = (unsigned short*)(h + (size_t)N_NODES * 32); // 16384 ushort

    // zero cnt + agg3 + agg4h (contiguous at front of ws)
    size_t zero_bytes = (size_t)N_NODES * (1 + 32 + 32) * sizeof(float);
    hipMemsetAsync(d_ws, 0, zero_bytes, stream);

    wpack3_kernel<<<8, 256, 0, stream>>>(Wl3, Wr3, bpack);
    count_kernel<<<(N_EDGES + 255) / 256, 256, 0, stream>>>(ei, cnt);
    proj3_mfma<<<(N_NODES + 63) / 64, 256, 0, stream>>>(x, bpack, xl, xr);
    scatter32_kernel<<<(N_EDGES * 32 + 255) / 256, 256, 0, stream>>>(ei, xl, agg3);
    h_kernel<<<(N_NODES * 8 + 255) / 256, 256, 0, stream>>>(agg3, xr, cnt, b3, h);
    scatter32_kernel<<<(N_EDGES * 32 + 255) / 256, 256, 0, stream>>>(ei, h, agg4h);
    out_kernel<<<(N_NODES + 255) / 256, 256, 0, stream>>>(agg4h, h, cnt, Wl4, Wr4, b4, outf);
}

// Round 3
// 130.512 us; speedup vs baseline: 1.7796x; 1.0550x over previous
//
#include <hip/hip_runtime.h>

#define N_NODES 50000
#define N_EDGES 300000
#define D_FEAT 256
// Live computation (sage1/sage2 outputs are dead in the reference):
// h = relu(mean_agg(x)@Wl3 + x@Wr3 + b3)
// out = log_softmax(mean_agg(h)@Wl4 + h@Wr4 + b4)
// Projection commutes with mean -> project first (256->32 via MFMA), then
// aggregate in 32-dim space. Aggregation via CSR-build + gather (no f32
// atomics, no agg zero-init).

typedef __attribute__((ext_vector_type(8))) short bf16x8;
typedef __attribute__((ext_vector_type(4))) float f32x4;

__device__ __forceinline__ unsigned short f2bf(float f) {
    unsigned int u = __builtin_bit_cast(unsigned int, f);
    u += 0x7fffu + ((u >> 16) & 1u);   // round-to-nearest-even
    return (unsigned short)(u >> 16);
}

// ---------------- CSR build ----------------

__global__ __launch_bounds__(256) void zero_hist(int* __restrict__ hist) {
    int i = blockIdx.x * 256 + threadIdx.x;
    if (i < N_NODES) hist[i] = 0;
}

__global__ __launch_bounds__(256) void hist_kernel(const int* __restrict__ ei,
                                                   int* __restrict__ hist) {
    int e = blockIdx.x * 256 + threadIdx.x;
    if (e < N_EDGES) atomicAdd(&hist[ei[N_EDGES + e]], 1);
}

// per-block exclusive scan: partial[i] = excl-scan within block, bsum[b] = block total
__global__ __launch_bounds__(256) void scan1_kernel(const int* __restrict__ hist,
        int* __restrict__ partial, int* __restrict__ bsum) {
    __shared__ int s[256];
    int t = threadIdx.x, g = blockIdx.x * 256 + t;
    int v = (g < N_NODES) ? hist[g] : 0;
    s[t] = v;
    __syncthreads();
    int acc = v;
#pragma unroll
    for (int off = 1; off < 256; off <<= 1) {
        int add = (t >= off) ? s[t - off] : 0;
        __syncthreads();
        acc += add;
        s[t] = acc;
        __syncthreads();
    }
    if (g < N_NODES) partial[g] = acc - v;       // exclusive
    if (t == 255) bsum[blockIdx.x] = acc;        // inclusive total
}

// single block: exclusive scan of block sums (nb <= 256)
__global__ __launch_bounds__(256) void scan2_kernel(const int* __restrict__ bsum,
        int* __restrict__ boff, int nb) {
    __shared__ int s[256];
    int t = threadIdx.x;
    int v = (t < nb) ? bsum[t] : 0;
    s[t] = v;
    __syncthreads();
    int acc = v;
#pragma unroll
    for (int off = 1; off < 256; off <<= 1) {
        int add = (t >= off) ? s[t - off] : 0;
        __syncthreads();
        acc += add;
        s[t] = acc;
        __syncthreads();
    }
    if (t < nb) boff[t] = acc - v;
}

__global__ __launch_bounds__(256) void scan3_kernel(const int* __restrict__ partial,
        const int* __restrict__ boff, int* __restrict__ rowptr, int* __restrict__ cursor) {
    int g = blockIdx.x * 256 + threadIdx.x;
    if (g < N_NODES) {
        int v = partial[g] + boff[blockIdx.x];
        rowptr[g] = v;
        cursor[g] = v;
    }
    if (g == 0) rowptr[N_NODES] = N_EDGES;
}

__global__ __launch_bounds__(256) void fill_kernel(const int* __restrict__ ei,
        int* __restrict__ cursor, int* __restrict__ csr) {
    int e = blockIdx.x * 256 + threadIdx.x;
    if (e < N_EDGES) {
        int d = ei[N_EDGES + e];
        int pos = atomicAdd(&cursor[d], 1);
        csr[pos] = ei[e];
    }
}

// ---------------- layer 3 projection (bf16 MFMA) ----------------

// Pack [Wl3 | Wr3] (256x64 f32) into bf16 B-fragment order:
// bp[((nt*8+ks)*64+lane)*8 + j] = W(k= ks*32+(lane>>4)*8+j, c= nt*16+(lane&15))
__global__ __launch_bounds__(256) void wpack3_kernel(const float* __restrict__ Wl,
        const float* __restrict__ Wr, unsigned short* __restrict__ bp) {
    int t = blockIdx.x * 256 + threadIdx.x;
    if (t >= 2048) return;
    int lane = t & 63;
    int ks = (t >> 6) & 7;
    int nt = t >> 9;
    int c = nt * 16 + (lane & 15);
    int kbase = ks * 32 + (lane >> 4) * 8;
    unsigned short o[8];
#pragma unroll
    for (int j = 0; j < 8; ++j) {
        int k = kbase + j;
        float v = (c < 32) ? Wl[k * 32 + c] : Wr[k * 32 + (c - 32)];
        o[j] = f2bf(v);
    }
    uint4 pk;
    pk.x = (unsigned)o[0] | ((unsigned)o[1] << 16);
    pk.y = (unsigned)o[2] | ((unsigned)o[3] << 16);
    pk.z = (unsigned)o[4] | ((unsigned)o[5] << 16);
    pk.w = (unsigned)o[6] | ((unsigned)o[7] << 16);
    ((uint4*)bp)[t] = pk;
}

// xl = x @ Wl3, xr = x @ Wr3 via bf16 MFMA; 4 waves/block, 16 rows/wave.
__global__ __launch_bounds__(256) void proj3_mfma(const float* __restrict__ x,
        const unsigned short* __restrict__ bp,
        float* __restrict__ xl, float* __restrict__ xr) {
    const int lane = threadIdx.x & 63;
    const int wv = threadIdx.x >> 6;
    const int row0 = blockIdx.x * 64 + wv * 16;
    const int arow = row0 + (lane & 15);
    const int kq = lane >> 4;
    const bool valid = arow < N_NODES;

    bf16x8 a[8];
    const float* xp = x + (size_t)arow * D_FEAT + kq * 8;
#pragma unroll
    for (int ks = 0; ks < 8; ++ks) {
        float4 p0, p1;
        if (valid) {
            p0 = *(const float4*)(xp + ks * 32);
            p1 = *(const float4*)(xp + ks * 32 + 4);
        } else {
            p0 = make_float4(0.f, 0.f, 0.f, 0.f);
            p1 = p0;
        }
        bf16x8 av;
        av[0] = (short)f2bf(p0.x); av[1] = (short)f2bf(p0.y);
        av[2] = (short)f2bf(p0.z); av[3] = (short)f2bf(p0.w);
        av[4] = (short)f2bf(p1.x); av[5] = (short)f2bf(p1.y);
        av[6] = (short)f2bf(p1.z); av[7] = (short)f2bf(p1.w);
        a[ks] = av;
    }

    f32x4 acc[4];
#pragma unroll
    for (int nt = 0; nt < 4; ++nt) acc[nt] = (f32x4){0.f, 0.f, 0.f, 0.f};

    const uint4* bq = (const uint4*)bp;
#pragma unroll
    for (int nt = 0; nt < 4; ++nt) {
#pragma unroll
        for (int ks = 0; ks < 8; ++ks) {
            bf16x8 b = __builtin_bit_cast(bf16x8, bq[(nt * 8 + ks) * 64 + lane]);
            acc[nt] = __builtin_amdgcn_mfma_f32_16x16x32_bf16(a[ks], b, acc[nt], 0, 0, 0);
        }
    }

    // C/D: col = lane&15, row = (lane>>4)*4 + reg
    const int orow = row0 + (lane >> 4) * 4;
    const int ocol = lane & 15;
#pragma unroll
    for (int nt = 0; nt < 4; ++nt) {
        float* dst = (nt < 2) ? xl : xr;
        const int cc = (nt & 1) * 16 + ocol;
#pragma unroll
        for (int i = 0; i < 4; ++i) {
            int r = orow + i;
            if (r < N_NODES) dst[(size_t)r * 32 + cc] = acc[nt][i];
        }
    }
}

// ---------------- gather aggregations ----------------

// thread = (node, col): h[n][c] = relu( (sum_{src in N(n)} xl[src][c]) / deg + xr[n][c] + b3[c] )
__global__ __launch_bounds__(256) void h_gather(const int* __restrict__ rowptr,
        const int* __restrict__ csr, const float* __restrict__ xl,
        const float* __restrict__ xr, const float* __restrict__ b3,
        float* __restrict__ h) {
    int gid = blockIdx.x * 256 + threadIdx.x;
    int n = gid >> 5, c = gid & 31;
    if (n >= N_NODES) return;
    int beg = rowptr[n], end = rowptr[n + 1];
    float sum = 0.0f;
    for (int i = beg; i < end; ++i) {
        int src = csr[i];               // broadcast across the 32 lanes
        sum += xl[(size_t)src * 32 + c];
    }
    float inv = 1.0f / (float)max(end - beg, 1);
    h[gid] = fmaxf(fmaf(sum, inv, xr[gid] + b3[c]), 0.0f);
}

// thread = (node, col): m4[n][c] = (sum_{src in N(n)} h[src][c]) / deg
__global__ __launch_bounds__(256) void m4_gather(const int* __restrict__ rowptr,
        const int* __restrict__ csr, const float* __restrict__ h,
        float* __restrict__ m4) {
    int gid = blockIdx.x * 256 + threadIdx.x;
    int n = gid >> 5, c = gid & 31;
    if (n >= N_NODES) return;
    int beg = rowptr[n], end = rowptr[n + 1];
    float sum = 0.0f;
    for (int i = beg; i < end; ++i) {
        int src = csr[i];
        sum += h[(size_t)src * 32 + c];
    }
    m4[gid] = sum / (float)max(end - beg, 1);
}

// ---------------- output layer ----------------

// out = log_softmax(m4 @ Wl4 + h @ Wr4 + b4)
__global__ __launch_bounds__(256) void out_kernel(const float* __restrict__ m4,
        const float* __restrict__ h, const float* __restrict__ Wl4,
        const float* __restrict__ Wr4, const float* __restrict__ b4,
        float* __restrict__ out) {
    __shared__ float w[32][80];
    const int tid = threadIdx.x;
    for (int i = tid; i < 32 * 80; i += 256) {
        int k = i / 80, c = i - k * 80;
        w[k][c] = (c < 40) ? Wl4[k * 40 + c] : Wr4[k * 40 + (c - 40)];
    }
    __syncthreads();
    const int node = blockIdx.x * 256 + tid;
    if (node >= N_NODES) return;
    float acc[40];
#pragma unroll
    for (int c = 0; c < 40; ++c) acc[c] = b4[c];
    const float4* ap = (const float4*)(m4 + (size_t)node * 32);
    const float4* hp = (const float4*)(h + (size_t)node * 32);
#pragma unroll
    for (int q = 0; q < 8; ++q) {
        float4 av = ap[q];
        float4 hv = hp[q];
        float mk[4] = {av.x, av.y, av.z, av.w};
        float hk[4] = {hv.x, hv.y, hv.z, hv.w};
#pragma unroll
        for (int j = 0; j < 4; ++j) {
            const int k = q * 4 + j;
#pragma unroll
            for (int c4 = 0; c4 < 10; ++c4) {
                float4 wl = *(const float4*)&w[k][c4 * 4];
                float4 wr = *(const float4*)&w[k][40 + c4 * 4];
                acc[c4 * 4 + 0] += mk[j] * wl.x + hk[j] * wr.x;
                acc[c4 * 4 + 1] += mk[j] * wl.y + hk[j] * wr.y;
                acc[c4 * 4 + 2] += mk[j] * wl.z + hk[j] * wr.z;
                acc[c4 * 4 + 3] += mk[j] * wl.w + hk[j] * wr.w;
            }
        }
    }
    float m = acc[0];
#pragma unroll
    for (int c = 1; c < 40; ++c) m = fmaxf(m, acc[c]);
    float s = 0.0f;
#pragma unroll
    for (int c = 0; c < 40; ++c) s += expf(acc[c] - m);
    const float ls = logf(s) + m;
    float4* op = (float4*)(out + (size_t)node * 40);
#pragma unroll
    for (int q = 0; q < 10; ++q)
        op[q] = make_float4(acc[q * 4 + 0] - ls, acc[q * 4 + 1] - ls,
                            acc[q * 4 + 2] - ls, acc[q * 4 + 3] - ls);
}

extern "C" void kernel_launch(void* const* d_in, const int* in_sizes, int n_in,
                              void* d_out, int out_size, void* d_ws, size_t ws_size,
                              hipStream_t stream) {
    const float* x   = (const float*)d_in[0];
    const int*   ei  = (const int*)d_in[1];
    const float* Wl3 = (const float*)d_in[8];
    const float* Wr3 = (const float*)d_in[9];
    const float* b3  = (const float*)d_in[10];
    const float* Wl4 = (const float*)d_in[11];
    const float* Wr4 = (const float*)d_in[12];
    const float* b4  = (const float*)d_in[13];
    float* outf = (float*)d_out;

    const int NB_NODES = (N_NODES + 255) / 256;   // 196
    const int NB_EDGES = (N_EDGES + 255) / 256;   // 1172

    char* p = (char*)d_ws;
    int* hist    = (int*)p;            p += sizeof(int) * N_NODES;
    int* partial = (int*)p;            p += sizeof(int) * N_NODES;
    int* bsum    = (int*)p;            p += sizeof(int) * 256;
    int* boff    = (int*)p;            p += sizeof(int) * 256;
    int* rowptr  = (int*)p;            p += sizeof(int) * (N_NODES + 1);
    int* cursor  = (int*)p;            p += sizeof(int) * N_NODES;
    int* csr     = (int*)p;            p += sizeof(int) * N_EDGES;
    float* xl    = (float*)p;          p += sizeof(float) * (size_t)N_NODES * 32;
    float* xr    = (float*)p;          p += sizeof(float) * (size_t)N_NODES * 32;
    float* h     = (float*)p;          p += sizeof(float) * (size_t)N_NODES * 32;
    float* m4    = (float*)p;          p += sizeof(float) * (size_t)N_NODES * 32;
    unsigned short* bpack = (unsigned short*)p;   // 16384 ushorts

    // projection path
    wpack3_kernel<<<8, 256, 0, stream>>>(Wl3, Wr3, bpack);
    proj3_mfma<<<(N_NODES + 63) / 64, 256, 0, stream>>>(x, bpack, xl, xr);

    // CSR build
    zero_hist<<<NB_NODES, 256, 0, stream>>>(hist);
    hist_kernel<<<NB_EDGES, 256, 0, stream>>>(ei, hist);
    scan1_kernel<<<NB_NODES, 256, 0, stream>>>(hist, partial, bsum);
    scan2_kernel<<<1, 256, 0, stream>>>(bsum, boff, NB_NODES);
    scan3_kernel<<<NB_NODES, 256, 0, stream>>>(partial, boff, rowptr, cursor);
    fill_kernel<<<NB_EDGES, 256, 0, stream>>>(ei, cursor, csr);

    // aggregation + epilogues
    h_gather<<<(N_NODES * 32 + 255) / 256, 256, 0, stream>>>(rowptr, csr, xl, xr, b3, h);
    m4_gather<<<(N_NODES * 32 + 255) / 256, 256, 0, stream>>>(rowptr, csr, h, m4);
    out_kernel<<<NB_NODES, 256, 0, stream>>>(m4, h, Wl4, Wr4, b4, outf);
}